// Round 1
// baseline (183.879 us; speedup 1.0000x reference)
//
#include <hip/hip_runtime.h>

// ---------------------------------------------------------------------------
// Sizes (fixed by the problem)
// ---------------------------------------------------------------------------
#define M_ROWS    4096
#define IN_DIM    512
#define NEURONS   1024
#define OUT_DIM   512
#define NUM_BASIS 18     // NUM_KNOTS + DEGREE - 1

// ---------------------------------------------------------------------------
// Tiled fp32 GEMM: C[M,N] = A[M,K] @ B[K,N] + bias[N], optional ReLU.
// BM=128, BN=64, BK=16, 256 threads, 8x4 micro-tile per thread.
// ---------------------------------------------------------------------------
#define BM 128
#define BN 64
#define BKK 16

__global__ __launch_bounds__(256) void gemm_bias(
    const float* __restrict__ A, const float* __restrict__ B,
    const float* __restrict__ bias, float* __restrict__ C,
    int M, int N, int K, int do_relu)
{
    // +4 pad keeps float4 alignment (132 % 4 == 0) and spreads banks
    __shared__ float As[BKK][BM + 4];
    __shared__ float Bs[BKK][BN];

    const int tid = threadIdx.x;
    const int tx  = tid & 15;   // 0..15 -> col group (4 cols)
    const int ty  = tid >> 4;   // 0..15 -> row group (8 rows)

    const float* Ablk = A + (size_t)(blockIdx.y) * BM * K;
    const float* Bblk = B + (size_t)(blockIdx.x) * BN;

    float acc[8][4];
#pragma unroll
    for (int i = 0; i < 8; ++i)
#pragma unroll
        for (int j = 0; j < 4; ++j) acc[i][j] = 0.f;

    for (int k0 = 0; k0 < K; k0 += BKK) {
        // Load A tile: 128 rows x 16 cols = 512 float4s, 2 per thread.
#pragma unroll
        for (int l = 0; l < 2; ++l) {
            int lin = tid + l * 256;
            int r   = lin >> 2;          // 0..127
            int c4  = (lin & 3) * 4;     // 0,4,8,12
            float4 av = *reinterpret_cast<const float4*>(
                Ablk + (size_t)r * K + k0 + c4);
            As[c4 + 0][r] = av.x;
            As[c4 + 1][r] = av.y;
            As[c4 + 2][r] = av.z;
            As[c4 + 3][r] = av.w;
        }
        // Load B tile: 16 rows x 64 cols = 256 float4s, 1 per thread.
        {
            int r  = tid >> 4;           // 0..15
            int c4 = (tid & 15) * 4;     // 0..60
            float4 bv = *reinterpret_cast<const float4*>(
                Bblk + (size_t)(k0 + r) * N + c4);
            *reinterpret_cast<float4*>(&Bs[r][c4]) = bv;
        }
        __syncthreads();

#pragma unroll
        for (int kk = 0; kk < BKK; ++kk) {
            float4 a0 = *reinterpret_cast<const float4*>(&As[kk][ty * 8]);
            float4 a1 = *reinterpret_cast<const float4*>(&As[kk][ty * 8 + 4]);
            float4 bb = *reinterpret_cast<const float4*>(&Bs[kk][tx * 4]);
            float a[8] = {a0.x, a0.y, a0.z, a0.w, a1.x, a1.y, a1.z, a1.w};
            float b[4] = {bb.x, bb.y, bb.z, bb.w};
#pragma unroll
            for (int i = 0; i < 8; ++i)
#pragma unroll
                for (int j = 0; j < 4; ++j)
                    acc[i][j] = fmaf(a[i], b[j], acc[i][j]);
        }
        __syncthreads();
    }

    const int crow0 = blockIdx.y * BM + ty * 8;
    const int ccol0 = blockIdx.x * BN + tx * 4;
    float4 bv = *reinterpret_cast<const float4*>(bias + ccol0);
#pragma unroll
    for (int i = 0; i < 8; ++i) {
        float4 v;
        v.x = acc[i][0] + bv.x;
        v.y = acc[i][1] + bv.y;
        v.z = acc[i][2] + bv.z;
        v.w = acc[i][3] + bv.w;
        if (do_relu) {
            v.x = fmaxf(v.x, 0.f); v.y = fmaxf(v.y, 0.f);
            v.z = fmaxf(v.z, 0.f); v.w = fmaxf(v.w, 0.f);
        }
        *reinterpret_cast<float4*>(C + (size_t)(crow0 + i) * N + ccol0) = v;
    }
}

// ---------------------------------------------------------------------------
// Fused: per-row min/max norm -> cubic B-spline basis (local 4-wide de Boor)
// -> dot with coeff row -> + sp_bias.   One block (256 thr) per row of 1024.
// ---------------------------------------------------------------------------
__global__ __launch_bounds__(256) void norm_spline(
    const float* __restrict__ H, const float* __restrict__ coeff,
    const float* __restrict__ spb, float* __restrict__ SP)
{
    const int row = blockIdx.x;
    const int tid = threadIdx.x;
    const float* hr = H + (size_t)row * NEURONS;

    float4 v = reinterpret_cast<const float4*>(hr)[tid];
    float lmn = fminf(fminf(v.x, v.y), fminf(v.z, v.w));
    float lmx = fmaxf(fmaxf(v.x, v.y), fmaxf(v.z, v.w));
#pragma unroll
    for (int m = 32; m; m >>= 1) {
        lmn = fminf(lmn, __shfl_xor(lmn, m));
        lmx = fmaxf(lmx, __shfl_xor(lmx, m));
    }
    __shared__ float smn[4], smx[4];
    if ((tid & 63) == 0) { smn[tid >> 6] = lmn; smx[tid >> 6] = lmx; }
    __syncthreads();
    const float mn = fminf(fminf(smn[0], smn[1]), fminf(smn[2], smn[3]));
    const float mx = fmaxf(fmaxf(smx[0], smx[1]), fmaxf(smx[2], smx[3]));
    const float inv = 1.0f / (mx - mn + 1e-8f);

    const float hk = 1.0f / 15.0f;
    const float vv[4] = {v.x, v.y, v.z, v.w};
    float out[4];

#pragma unroll
    for (int e = 0; e < 4; ++e) {
        const int n = tid * 4 + e;
        const float u = (vv[e] - mn) * inv;       // in [0, 1]
        int ii = (int)floorf(u * 15.0f);
        ii = ii < 0 ? 0 : (ii > 14 ? 14 : ii);    // grid interval 0..14
        const int i = ii + 3;                     // knot interval index

        // de Boor over the nonzero window; identical to full recursion since
        // the dropped terms are exactly zero.
        float Bv[4] = {1.f, 0.f, 0.f, 0.f};
#pragma unroll
        for (int p = 1; p <= 3; ++p) {
            const float dinv = 1.0f / ((float)p * hk);
            float nb[4];
#pragma unroll
            for (int j = 3; j >= 0; --j) {
                if (j > p) { nb[j] = 0.f; continue; }
                const int m = i - p + j;          // basis/knot index
                const float tm   = (float)(m - 3) * hk;          // t[m]
                const float tmp1 = (float)(m + p + 1 - 3) * hk;  // t[m+p+1]
                const float left  = (j > 0) ? (u - tm)   * Bv[j - 1] : 0.f;
                const float right = (j < p) ? (tmp1 - u) * Bv[j]     : 0.f;
                nb[j] = (left + right) * dinv;
            }
#pragma unroll
            for (int j = 0; j < 4; ++j) Bv[j] = nb[j];
        }

        const float* c = coeff + (size_t)n * NUM_BASIS + ii;
        out[e] = fmaf(Bv[0], c[0],
                 fmaf(Bv[1], c[1],
                 fmaf(Bv[2], c[2], Bv[3] * c[3]))) + spb[n];
    }
    reinterpret_cast<float4*>(SP + (size_t)row * NEURONS)[tid] =
        make_float4(out[0], out[1], out[2], out[3]);
}

// ---------------------------------------------------------------------------
extern "C" void kernel_launch(void* const* d_in, const int* in_sizes, int n_in,
                              void* d_out, int out_size, void* d_ws, size_t ws_size,
                              hipStream_t stream)
{
    const float* x     = (const float*)d_in[0];
    const float* W1    = (const float*)d_in[1];
    const float* b1    = (const float*)d_in[2];
    const float* coeff = (const float*)d_in[3];
    const float* spb   = (const float*)d_in[4];
    const float* W2    = (const float*)d_in[5];
    const float* b2    = (const float*)d_in[6];
    float* out = (float*)d_out;

    float* h  = (float*)d_ws;                       // 4096*1024 f32 = 16 MB
    float* sp = h + (size_t)M_ROWS * NEURONS;       // another 16 MB

    dim3 blk(256);
    // h = x @ W1 + b1
    gemm_bias<<<dim3(NEURONS / BN, M_ROWS / BM), blk, 0, stream>>>(
        x, W1, b1, h, M_ROWS, NEURONS, IN_DIM, 0);
    // sp = spline(norm(h)) . coeff + sp_bias
    norm_spline<<<dim3(M_ROWS), blk, 0, stream>>>(h, coeff, spb, sp);
    // out = relu(sp @ W2 + b2)
    gemm_bias<<<dim3(OUT_DIM / BN, M_ROWS / BM), blk, 0, stream>>>(
        sp, W2, b2, out, M_ROWS, OUT_DIM, NEURONS, 1);
}

// Round 2
// 73.733 us; speedup vs baseline: 2.4938x; 2.4938x over previous
//
#include <hip/hip_runtime.h>
#include <hip/hip_bf16.h>

#define M_ROWS  4096
#define IN_DIM  512
#define NEURONS 1024
#define OUT_DIM 512

typedef __attribute__((ext_vector_type(8))) short          s16x8;
typedef __attribute__((ext_vector_type(8))) unsigned short u16x8;
typedef __attribute__((ext_vector_type(4))) float          f32x4;

__device__ __forceinline__ unsigned short f2b(float v) {
    __hip_bfloat16 b = __float2bfloat16(v);
    return __builtin_bit_cast(unsigned short, b);
}
__device__ __forceinline__ float b2f(unsigned short u) {
    return __bfloat162float(__builtin_bit_cast(__hip_bfloat16, u));
}

// ---------------------------------------------------------------------------
// x (fp32) -> hi/lo bf16, same layout. 8 elements per thread.
// ---------------------------------------------------------------------------
__global__ __launch_bounds__(256) void convert_split(
    const float* __restrict__ in, unsigned short* __restrict__ hi,
    unsigned short* __restrict__ lo, int n8)
{
    int i = blockIdx.x * 256 + threadIdx.x;
    if (i >= n8) return;
    const float4* p = (const float4*)in;
    float4 a = p[i * 2], b = p[i * 2 + 1];
    float v[8] = {a.x, a.y, a.z, a.w, b.x, b.y, b.z, b.w};
    u16x8 h, l;
#pragma unroll
    for (int j = 0; j < 8; ++j) {
        unsigned short hb = f2b(v[j]);
        h[j] = hb;
        l[j] = f2b(v[j] - b2f(hb));
    }
    ((u16x8*)hi)[i] = h;
    ((u16x8*)lo)[i] = l;
}

// ---------------------------------------------------------------------------
// W [R][C] fp32 -> Wt [C][R] bf16 (hi, and lo if SPLIT). 32x32 LDS tiles.
// ---------------------------------------------------------------------------
template<bool SPLIT>
__global__ __launch_bounds__(256) void transpose_split(
    const float* __restrict__ in, unsigned short* __restrict__ hi,
    unsigned short* __restrict__ lo, int R, int C)
{
    __shared__ float S[32][33];
    const int c0 = blockIdx.x * 32, r0 = blockIdx.y * 32;
    const int tr = threadIdx.x >> 3;
    const int tc = (threadIdx.x & 7) * 4;
    float4 v = *(const float4*)&in[(size_t)(r0 + tr) * C + c0 + tc];
    S[tr][tc + 0] = v.x; S[tr][tc + 1] = v.y;
    S[tr][tc + 2] = v.z; S[tr][tc + 3] = v.w;
    __syncthreads();
    float o[4] = {S[tc + 0][tr], S[tc + 1][tr], S[tc + 2][tr], S[tc + 3][tr]};
    ushort4 h, l;
    h.x = f2b(o[0]); h.y = f2b(o[1]); h.z = f2b(o[2]); h.w = f2b(o[3]);
    if (SPLIT) {
        l.x = f2b(o[0] - b2f(h.x)); l.y = f2b(o[1] - b2f(h.y));
        l.z = f2b(o[2] - b2f(h.z)); l.w = f2b(o[3] - b2f(h.w));
    }
    size_t ob = (size_t)(c0 + tr) * R + r0 + tc;
    *(ushort4*)&hi[ob] = h;
    if (SPLIT) *(ushort4*)&lo[ob] = l;
}

// ---------------------------------------------------------------------------
// MFMA GEMM: C[M,N] = A @ Bt^T + bias, A row-major [M][K] bf16 (hi/lo pair if
// SPLIT), Bt row-major [N][K] bf16. 128x128 block, 4 waves of 64x64, BK=32,
// reg-staged LDS double-buffer, one barrier per K-step.
// ---------------------------------------------------------------------------
template<bool SPLIT, bool RELU>
__global__ __launch_bounds__(256) void gemm_mfma(
    const unsigned short* __restrict__ Ah, const unsigned short* __restrict__ Al,
    const unsigned short* __restrict__ Bh, const unsigned short* __restrict__ Bl,
    const float* __restrict__ bias, float* __restrict__ C,
    int M, int N, int K)
{
    constexpr int BM = 128, BN = 128;
    constexpr int NP = SPLIT ? 2 : 1;
    // [buf][hi/lo plane][A tile BM*32 then B tile BN*32] (row-major [row][32])
    __shared__ unsigned short lds[2][NP][(BM + BN) * 32];

    const int t    = threadIdx.x;
    const int lane = t & 63;
    const int l15  = lane & 15;
    const int lhi  = lane >> 4;
    const int wid  = t >> 6;
    const int wm   = wid >> 1, wn = wid & 1;
    const int m0   = blockIdx.y * BM, n0 = blockIdx.x * BN;

    // staging map: thread t -> chunks {t, t+256}; chunk c -> row c>>2, k (c&3)*8
    const int srow = t >> 2;
    const int sk   = (t & 3) * 8;
    const size_t offA0 = (size_t)(m0 + srow) * K + sk;
    const size_t offA1 = offA0 + (size_t)64 * K;
    const size_t offB0 = (size_t)(n0 + srow) * K + sk;
    const size_t offB1 = offB0 + (size_t)64 * K;

    u16x8 rAh[2], rAl[2], rBh[2], rBl[2];

    auto gload = [&](int k0) {
        rAh[0] = *(const u16x8*)(Ah + offA0 + k0);
        rAh[1] = *(const u16x8*)(Ah + offA1 + k0);
        rBh[0] = *(const u16x8*)(Bh + offB0 + k0);
        rBh[1] = *(const u16x8*)(Bh + offB1 + k0);
        if (SPLIT) {
            rAl[0] = *(const u16x8*)(Al + offA0 + k0);
            rAl[1] = *(const u16x8*)(Al + offA1 + k0);
            rBl[0] = *(const u16x8*)(Bl + offB0 + k0);
            rBl[1] = *(const u16x8*)(Bl + offB1 + k0);
        }
    };
    auto swrite = [&](int buf) {
        unsigned short* P = &lds[buf][0][0];
        *(u16x8*)&P[t * 8]              = rAh[0];
        *(u16x8*)&P[2048 + t * 8]       = rAh[1];
        *(u16x8*)&P[4096 + t * 8]       = rBh[0];
        *(u16x8*)&P[4096 + 2048 + t * 8]= rBh[1];
        if (SPLIT) {
            unsigned short* Q = &lds[buf][NP - 1][0];
            *(u16x8*)&Q[t * 8]              = rAl[0];
            *(u16x8*)&Q[2048 + t * 8]       = rAl[1];
            *(u16x8*)&Q[4096 + t * 8]       = rBl[0];
            *(u16x8*)&Q[4096 + 2048 + t * 8]= rBl[1];
        }
    };

    f32x4 acc[4][4];
#pragma unroll
    for (int i = 0; i < 4; ++i)
#pragma unroll
        for (int j = 0; j < 4; ++j) acc[i][j] = (f32x4)0.f;

    const int T = K / 32;
    gload(0);
    swrite(0);
    gload(32);
    __syncthreads();

    int cur = 0;
    for (int tt = 0; tt < T; ++tt) {
        if (tt + 1 < T) {
            swrite(cur ^ 1);                       // tile tt+1 -> other buffer
            if (tt + 2 < T) gload((tt + 2) * 32);  // issue loads for tile tt+2
        }
        const unsigned short* H = &lds[cur][0][0];
        const unsigned short* L = &lds[cur][NP - 1][0];

        s16x8 bh[4], bl[4];
#pragma unroll
        for (int nj = 0; nj < 4; ++nj) {
            int bi = 4096 + (wn * 64 + nj * 16 + l15) * 32 + lhi * 8;
            bh[nj] = *(const s16x8*)&H[bi];
            if (SPLIT) bl[nj] = *(const s16x8*)&L[bi];
        }
#pragma unroll
        for (int mi = 0; mi < 4; ++mi) {
            int ai = (wm * 64 + mi * 16 + l15) * 32 + lhi * 8;
            s16x8 ah = *(const s16x8*)&H[ai];
            s16x8 al = ah;
            if (SPLIT) al = *(const s16x8*)&L[ai];
#pragma unroll
            for (int nj = 0; nj < 4; ++nj) {
                acc[mi][nj] = __builtin_amdgcn_mfma_f32_16x16x32_bf16(
                    ah, bh[nj], acc[mi][nj], 0, 0, 0);
                if (SPLIT) {
                    acc[mi][nj] = __builtin_amdgcn_mfma_f32_16x16x32_bf16(
                        al, bh[nj], acc[mi][nj], 0, 0, 0);
                    acc[mi][nj] = __builtin_amdgcn_mfma_f32_16x16x32_bf16(
                        ah, bl[nj], acc[mi][nj], 0, 0, 0);
                }
            }
        }
        __syncthreads();
        cur ^= 1;
    }

    // epilogue: C/D map row = lhi*4 + j, col = l15 (m89-verified)
#pragma unroll
    for (int mi = 0; mi < 4; ++mi) {
#pragma unroll
        for (int nj = 0; nj < 4; ++nj) {
            int row0 = m0 + wm * 64 + mi * 16 + lhi * 4;
            int col  = n0 + wn * 64 + nj * 16 + l15;
            float bv = bias[col];
#pragma unroll
            for (int j = 0; j < 4; ++j) {
                float v = acc[mi][nj][j] + bv;
                if (RELU) v = fmaxf(v, 0.f);
                C[(size_t)(row0 + j) * N + col] = v;
            }
        }
    }
}

// ---------------------------------------------------------------------------
// Per-row min/max norm -> cubic B-spline (local de Boor) -> coeff dot ->
// + sp_bias. One 256-thread block per row; outputs bf16.
// ---------------------------------------------------------------------------
__global__ __launch_bounds__(256) void norm_spline(
    const float* __restrict__ H, const float* __restrict__ coeff,
    const float* __restrict__ spb, unsigned short* __restrict__ SPH)
{
    const int row = blockIdx.x;
    const int tid = threadIdx.x;
    const float* hr = H + (size_t)row * NEURONS;

    float4 v = reinterpret_cast<const float4*>(hr)[tid];
    float lmn = fminf(fminf(v.x, v.y), fminf(v.z, v.w));
    float lmx = fmaxf(fmaxf(v.x, v.y), fmaxf(v.z, v.w));
#pragma unroll
    for (int m = 32; m; m >>= 1) {
        lmn = fminf(lmn, __shfl_xor(lmn, m));
        lmx = fmaxf(lmx, __shfl_xor(lmx, m));
    }
    __shared__ float smn[4], smx[4];
    if ((tid & 63) == 0) { smn[tid >> 6] = lmn; smx[tid >> 6] = lmx; }
    __syncthreads();
    const float mn = fminf(fminf(smn[0], smn[1]), fminf(smn[2], smn[3]));
    const float mx = fmaxf(fmaxf(smx[0], smx[1]), fmaxf(smx[2], smx[3]));
    const float inv = 1.0f / (mx - mn + 1e-8f);

    const float hk = 1.0f / 15.0f;
    const float vv[4] = {v.x, v.y, v.z, v.w};
    float out[4];

#pragma unroll
    for (int e = 0; e < 4; ++e) {
        const int n = tid * 4 + e;
        const float u = (vv[e] - mn) * inv;
        int ii = (int)floorf(u * 15.0f);
        ii = ii < 0 ? 0 : (ii > 14 ? 14 : ii);
        const int i = ii + 3;

        float Bv[4] = {1.f, 0.f, 0.f, 0.f};
#pragma unroll
        for (int p = 1; p <= 3; ++p) {
            const float dinv = 1.0f / ((float)p * hk);
            float nb[4];
#pragma unroll
            for (int j = 3; j >= 0; --j) {
                if (j > p) { nb[j] = 0.f; continue; }
                const int m = i - p + j;
                const float tm   = (float)(m - 3) * hk;
                const float tmp1 = (float)(m + p + 1 - 3) * hk;
                const float left  = (j > 0) ? (u - tm)   * Bv[j - 1] : 0.f;
                const float right = (j < p) ? (tmp1 - u) * Bv[j]     : 0.f;
                nb[j] = (left + right) * dinv;
            }
#pragma unroll
            for (int j = 0; j < 4; ++j) Bv[j] = nb[j];
        }

        const float* c = coeff + (size_t)n * 18 + ii;
        out[e] = fmaf(Bv[0], c[0],
                 fmaf(Bv[1], c[1],
                 fmaf(Bv[2], c[2], Bv[3] * c[3]))) + spb[n];
    }
    ushort4 o;
    o.x = f2b(out[0]); o.y = f2b(out[1]); o.z = f2b(out[2]); o.w = f2b(out[3]);
    ((ushort4*)(SPH + (size_t)row * NEURONS))[tid] = o;
}

// ---------------------------------------------------------------------------
extern "C" void kernel_launch(void* const* d_in, const int* in_sizes, int n_in,
                              void* d_out, int out_size, void* d_ws, size_t ws_size,
                              hipStream_t stream)
{
    const float* x     = (const float*)d_in[0];
    const float* W1    = (const float*)d_in[1];
    const float* b1    = (const float*)d_in[2];
    const float* coeff = (const float*)d_in[3];
    const float* spb   = (const float*)d_in[4];
    const float* W2    = (const float*)d_in[5];
    const float* b2    = (const float*)d_in[6];
    float* out = (float*)d_out;

    char* ws = (char*)d_ws;
    float*          h    = (float*)ws;                              // 16 MB
    unsigned short* W1th = (unsigned short*)(ws + (16u << 20));     // 1 MB
    unsigned short* W1tl = (unsigned short*)(ws + (17u << 20));     // 1 MB
    unsigned short* W2th = (unsigned short*)(ws + (18u << 20));     // 1 MB
    unsigned short* xh   = (unsigned short*)(ws + (19u << 20));     // 4 MB
    unsigned short* xl   = (unsigned short*)(ws + (23u << 20));     // 4 MB
    unsigned short* sph  = (unsigned short*)(ws + (19u << 20));     // 8 MB alias (after GEMM1)

    convert_split<<<dim3((M_ROWS * IN_DIM / 8) / 256), 256, 0, stream>>>(
        x, xh, xl, M_ROWS * IN_DIM / 8);
    transpose_split<true><<<dim3(NEURONS / 32, IN_DIM / 32), 256, 0, stream>>>(
        W1, W1th, W1tl, IN_DIM, NEURONS);
    transpose_split<false><<<dim3(OUT_DIM / 32, NEURONS / 32), 256, 0, stream>>>(
        W2, W2th, W2th, NEURONS, OUT_DIM);

    gemm_mfma<true, false><<<dim3(NEURONS / 128, M_ROWS / 128), 256, 0, stream>>>(
        xh, xl, W1th, W1tl, b1, h, M_ROWS, NEURONS, IN_DIM);

    norm_spline<<<dim3(M_ROWS), 256, 0, stream>>>(h, coeff, spb, sph);

    gemm_mfma<false, true><<<dim3(OUT_DIM / 128, M_ROWS / 128), 256, 0, stream>>>(
        sph, sph, W2th, W2th, b2, out, M_ROWS, OUT_DIM, NEURONS);
}

// Round 3
// 54.346 us; speedup vs baseline: 3.3835x; 1.3567x over previous
//
#include <hip/hip_runtime.h>

#define M_ROWS  4096
#define IN_DIM  512
#define NEURONS 1024
#define OUT_DIM 512

typedef _Float16 f16;
typedef __attribute__((ext_vector_type(8))) _Float16 f16x8;
typedef __attribute__((ext_vector_type(4))) _Float16 f16x4;
typedef __attribute__((ext_vector_type(4))) float    f32x4;

// ---------------------------------------------------------------------------
// Fused prep: [0,1024) convert x f32->f16; [1024,1536) transpose W1 -> f16;
// [1536,2048) transpose W2 -> f16.
// ---------------------------------------------------------------------------
__global__ __launch_bounds__(256) void prep(
    const float* __restrict__ x,  f16* __restrict__ xh,
    const float* __restrict__ W1, f16* __restrict__ W1t,
    const float* __restrict__ W2, f16* __restrict__ W2t)
{
    __shared__ float S[32][33];
    const int b = blockIdx.x, t = threadIdx.x;
    if (b < 1024) {
        int i = b * 256 + t;
        const float4* p = (const float4*)x;
        float4 a = p[i * 2], c = p[i * 2 + 1];
        f16x8 o = { (f16)a.x, (f16)a.y, (f16)a.z, (f16)a.w,
                    (f16)c.x, (f16)c.y, (f16)c.z, (f16)c.w };
        *(f16x8*)(xh + (size_t)i * 8) = o;
        return;
    }
    const float* src; f16* dst; int R, C, tile;
    if (b < 1536) { src = W1; dst = W1t; R = IN_DIM;  C = NEURONS; tile = b - 1024; }
    else          { src = W2; dst = W2t; R = NEURONS; C = OUT_DIM; tile = b - 1536; }
    const int ntx = C / 32;
    const int tx = tile % ntx, ty = tile / ntx;
    const int tr = t >> 3, tc = (t & 7) * 4;
    float4 v = *(const float4*)&src[(size_t)(ty * 32 + tr) * C + tx * 32 + tc];
    S[tr][tc + 0] = v.x; S[tr][tc + 1] = v.y;
    S[tr][tc + 2] = v.z; S[tr][tc + 3] = v.w;
    __syncthreads();
    f16x4 o = { (f16)S[tc + 0][tr], (f16)S[tc + 1][tr],
                (f16)S[tc + 2][tr], (f16)S[tc + 3][tr] };
    *(f16x4*)&dst[(size_t)(tx * 32 + tr) * R + ty * 32 + tc] = o;
}

// ---------------------------------------------------------------------------
// fp16 MFMA GEMM, m97 structure: global_load_lds(16B) -> linear LDS [row][32],
// double-buffered, ONE barrier per K-step. A [M][K] f16, Bt [N][K] f16.
// 4 waves; wave-tile (MI*16) x (NJ*16), waves arranged 2x2.
// ---------------------------------------------------------------------------
template<int BM, int BN, int MI, int NJ, bool RELU>
__global__ __launch_bounds__(256) void gemm_f16(
    const f16* __restrict__ A, const f16* __restrict__ Bt,
    const float* __restrict__ bias, float* __restrict__ C,
    int M, int N, int K)
{
    constexpr int nA = BM / 64;      // A-chunk loads per wave (1024B each)
    constexpr int nB = BN / 64;
    __shared__ f16 lds[2][(BM + BN) * 32];

    const int t    = threadIdx.x;
    const int lane = t & 63;
    const int l15  = lane & 15;
    const int lhi  = lane >> 4;
    const int wid  = t >> 6;
    const int wm   = wid >> 1, wn = wid & 1;

    // bijective XCD swizzle (nwg % 8 == 0)
    const int nwg  = gridDim.x * gridDim.y;
    const int flat = blockIdx.y * gridDim.x + blockIdx.x;
    const int swz  = (flat & 7) * (nwg >> 3) + (flat >> 3);
    const int m0   = (swz / gridDim.x) * BM;
    const int n0   = (swz % gridDim.x) * BN;

    const int srow = lane >> 2;        // 0..15
    const int skb  = (lane & 3) * 8;   // k element offset

    auto stage = [&](int buf, int kt) {
        f16* base = &lds[buf][0];
#pragma unroll
        for (int j = 0; j < nA; ++j) {
            int chunk = wid * nA + j;
            const f16* g = A + (size_t)(m0 + chunk * 16 + srow) * K + kt + skb;
            __builtin_amdgcn_global_load_lds(
                (const __attribute__((address_space(1))) void*)g,
                (__attribute__((address_space(3))) void*)(base + chunk * 512),
                16, 0, 0);
        }
#pragma unroll
        for (int j = 0; j < nB; ++j) {
            int chunk = wid * nB + j;
            const f16* g = Bt + (size_t)(n0 + chunk * 16 + srow) * K + kt + skb;
            __builtin_amdgcn_global_load_lds(
                (const __attribute__((address_space(1))) void*)g,
                (__attribute__((address_space(3))) void*)(base + BM * 32 + chunk * 512),
                16, 0, 0);
        }
    };

    f32x4 acc[MI][NJ];
#pragma unroll
    for (int i = 0; i < MI; ++i)
#pragma unroll
        for (int j = 0; j < NJ; ++j) acc[i][j] = (f32x4)0.f;

    const int T = K / 32;
    stage(0, 0);
    __syncthreads();

    int cur = 0;
    for (int tt = 0; tt < T; ++tt) {
        if (tt + 1 < T) stage(cur ^ 1, (tt + 1) * 32);
        const f16* L = &lds[cur][0];
        f16x8 bfr[NJ];
#pragma unroll
        for (int nj = 0; nj < NJ; ++nj)
            bfr[nj] = *(const f16x8*)
                &L[BM * 32 + (wn * NJ * 16 + nj * 16 + l15) * 32 + lhi * 8];
#pragma unroll
        for (int mi = 0; mi < MI; ++mi) {
            f16x8 afr = *(const f16x8*)
                &L[(wm * MI * 16 + mi * 16 + l15) * 32 + lhi * 8];
#pragma unroll
            for (int nj = 0; nj < NJ; ++nj)
                acc[mi][nj] = __builtin_amdgcn_mfma_f32_16x16x32_f16(
                    afr, bfr[nj], acc[mi][nj], 0, 0, 0);
        }
        __syncthreads();    // drains vmcnt(0): next tile staged; cur free to overwrite
        cur ^= 1;
    }

    // epilogue: C/D map col = l15, row = lhi*4 + j (dtype-independent)
#pragma unroll
    for (int mi = 0; mi < MI; ++mi) {
#pragma unroll
        for (int nj = 0; nj < NJ; ++nj) {
            int row0 = m0 + wm * MI * 16 + mi * 16 + lhi * 4;
            int col  = n0 + wn * NJ * 16 + nj * 16 + l15;
            float bv = bias[col];
#pragma unroll
            for (int j = 0; j < 4; ++j) {
                float v = acc[mi][nj][j] + bv;
                if (RELU) v = fmaxf(v, 0.f);
                C[(size_t)(row0 + j) * N + col] = v;
            }
        }
    }
}

// ---------------------------------------------------------------------------
// Per-row min/max norm -> cubic B-spline (local de Boor) -> coeff dot ->
// + sp_bias. One 256-thread block per row; outputs f16.
// ---------------------------------------------------------------------------
__global__ __launch_bounds__(256) void norm_spline(
    const float* __restrict__ H, const float* __restrict__ coeff,
    const float* __restrict__ spb, f16* __restrict__ SPH)
{
    const int row = blockIdx.x;
    const int tid = threadIdx.x;
    const float* hr = H + (size_t)row * NEURONS;

    float4 v = reinterpret_cast<const float4*>(hr)[tid];
    float lmn = fminf(fminf(v.x, v.y), fminf(v.z, v.w));
    float lmx = fmaxf(fmaxf(v.x, v.y), fmaxf(v.z, v.w));
#pragma unroll
    for (int m = 32; m; m >>= 1) {
        lmn = fminf(lmn, __shfl_xor(lmn, m));
        lmx = fmaxf(lmx, __shfl_xor(lmx, m));
    }
    __shared__ float smn[4], smx[4];
    if ((tid & 63) == 0) { smn[tid >> 6] = lmn; smx[tid >> 6] = lmx; }
    __syncthreads();
    const float mn = fminf(fminf(smn[0], smn[1]), fminf(smn[2], smn[3]));
    const float mx = fmaxf(fmaxf(smx[0], smx[1]), fmaxf(smx[2], smx[3]));
    const float inv = 1.0f / (mx - mn + 1e-8f);

    const float hk = 1.0f / 15.0f;
    const float vv[4] = {v.x, v.y, v.z, v.w};
    float out[4];

#pragma unroll
    for (int e = 0; e < 4; ++e) {
        const int n = tid * 4 + e;
        const float u = (vv[e] - mn) * inv;
        int ii = (int)floorf(u * 15.0f);
        ii = ii < 0 ? 0 : (ii > 14 ? 14 : ii);
        const int i = ii + 3;

        float Bv[4] = {1.f, 0.f, 0.f, 0.f};
#pragma unroll
        for (int p = 1; p <= 3; ++p) {
            const float dinv = 1.0f / ((float)p * hk);
            float nb[4];
#pragma unroll
            for (int j = 3; j >= 0; --j) {
                if (j > p) { nb[j] = 0.f; continue; }
                const int m = i - p + j;
                const float tm   = (float)(m - 3) * hk;
                const float tmp1 = (float)(m + p + 1 - 3) * hk;
                const float left  = (j > 0) ? (u - tm)   * Bv[j - 1] : 0.f;
                const float right = (j < p) ? (tmp1 - u) * Bv[j]     : 0.f;
                nb[j] = (left + right) * dinv;
            }
#pragma unroll
            for (int j = 0; j < 4; ++j) Bv[j] = nb[j];
        }

        const float* c = coeff + (size_t)n * 18 + ii;
        out[e] = fmaf(Bv[0], c[0],
                 fmaf(Bv[1], c[1],
                 fmaf(Bv[2], c[2], Bv[3] * c[3]))) + spb[n];
    }
    f16x4 o = { (f16)out[0], (f16)out[1], (f16)out[2], (f16)out[3] };
    ((f16x4*)(SPH + (size_t)row * NEURONS))[tid] = o;
}

// ---------------------------------------------------------------------------
extern "C" void kernel_launch(void* const* d_in, const int* in_sizes, int n_in,
                              void* d_out, int out_size, void* d_ws, size_t ws_size,
                              hipStream_t stream)
{
    const float* x     = (const float*)d_in[0];
    const float* W1    = (const float*)d_in[1];
    const float* b1    = (const float*)d_in[2];
    const float* coeff = (const float*)d_in[3];
    const float* spb   = (const float*)d_in[4];
    const float* W2    = (const float*)d_in[5];
    const float* b2    = (const float*)d_in[6];
    float* out = (float*)d_out;

    char* ws = (char*)d_ws;
    float* h   = (float*)ws;                          // 16 MB f32
    f16*   xh  = (f16*)(ws + (16u << 20));            //  4 MB
    f16*   W1t = (f16*)(ws + (20u << 20));            //  2 MB   [1024][512]
    f16*   W2t = (f16*)(ws + (22u << 20));            //  1 MB   [512][1024]
    f16*   sph = (f16*)(ws + (23u << 20));            //  8 MB   [4096][1024]

    prep<<<dim3(2048), 256, 0, stream>>>(x, xh, W1, W1t, W2, W2t);

    // h = x @ W1 + b1   (M=4096, N=1024, K=512), 128x64 tiles -> 512 blocks
    gemm_f16<128, 64, 4, 2, false><<<dim3(NEURONS / 64, M_ROWS / 128), 256, 0, stream>>>(
        xh, W1t, b1, h, M_ROWS, NEURONS, IN_DIM);

    norm_spline<<<dim3(M_ROWS), 256, 0, stream>>>(h, coeff, spb, sph);

    // out = relu(sp @ W2 + b2)  (M=4096, N=512, K=1024), 64x64 tiles -> 512 blocks
    gemm_f16<64, 64, 2, 2, true><<<dim3(OUT_DIM / 64, M_ROWS / 64), 256, 0, stream>>>(
        sph, W2t, b2, out, M_ROWS, OUT_DIM, NEURONS);
}

// Round 4
// 53.485 us; speedup vs baseline: 3.4380x; 1.0161x over previous
//
#include <hip/hip_runtime.h>

#define M_ROWS  4096
#define IN_DIM  512
#define NEURONS 1024
#define OUT_DIM 512

typedef _Float16 f16;
typedef __attribute__((ext_vector_type(8))) _Float16 f16x8;
typedef __attribute__((ext_vector_type(4))) _Float16 f16x4;
typedef __attribute__((ext_vector_type(4))) float    f32x4;

// monotone float<->uint key (total order preserved on unsigned compare)
__device__ __forceinline__ unsigned fkey(float f) {
    unsigned b = __float_as_uint(f);
    return b ^ ((b & 0x80000000u) ? 0xFFFFFFFFu : 0x80000000u);
}
__device__ __forceinline__ float fdec(unsigned k) {
    unsigned b = (k & 0x80000000u) ? (k ^ 0x80000000u) : ~k;
    return __uint_as_float(b);
}

// ---------------------------------------------------------------------------
// Fused prep:
//   [0,1024)     convert x f32 -> f16
//   [1024,1536)  transpose W1 [512][1024] -> W1t [1024][512] f16
//   [1536,2048)  transpose W2 [1024][512] -> W2t [512][1024] f16
//   [2048,2080)  init min/max key buffers (8192 uints)
// ---------------------------------------------------------------------------
__global__ __launch_bounds__(256) void prep(
    const float* __restrict__ x,  f16* __restrict__ xh,
    const float* __restrict__ W1, f16* __restrict__ W1t,
    const float* __restrict__ W2, f16* __restrict__ W2t,
    unsigned* __restrict__ keys)
{
    __shared__ float S[32][33];
    const int b = blockIdx.x, t = threadIdx.x;
    if (b < 1024) {
        int i = b * 256 + t;
        const float4* p = (const float4*)x;
        float4 a = p[i * 2], c = p[i * 2 + 1];
        f16x8 o = { (f16)a.x, (f16)a.y, (f16)a.z, (f16)a.w,
                    (f16)c.x, (f16)c.y, (f16)c.z, (f16)c.w };
        *(f16x8*)(xh + (size_t)i * 8) = o;
        return;
    }
    if (b >= 2048) {
        int i = (b - 2048) * 256 + t;      // 0..8191
        keys[i] = (i < 4096) ? 0xFFFFFFFFu : 0u;
        return;
    }
    const float* src; f16* dst; int R, C, tile;
    if (b < 1536) { src = W1; dst = W1t; R = IN_DIM;  C = NEURONS; tile = b - 1024; }
    else          { src = W2; dst = W2t; R = NEURONS; C = OUT_DIM; tile = b - 1536; }
    const int ntx = C / 32;
    const int tx = tile % ntx, ty = tile / ntx;
    const int tr = t >> 3, tc = (t & 7) * 4;
    float4 v = *(const float4*)&src[(size_t)(ty * 32 + tr) * C + tx * 32 + tc];
    S[tr][tc + 0] = v.x; S[tr][tc + 1] = v.y;
    S[tr][tc + 2] = v.z; S[tr][tc + 3] = v.w;
    __syncthreads();
    f16x4 o = { (f16)S[tc + 0][tr], (f16)S[tc + 1][tr],
                (f16)S[tc + 2][tr], (f16)S[tc + 3][tr] };
    *(f16x4*)&dst[(size_t)(tx * 32 + tr) * R + ty * 32 + tc] = o;
}

// ---------------------------------------------------------------------------
// fp16 MFMA GEMM, BK=64, global_load_lds(16B), linear LDS [row][64] halves,
// double-buffered, one barrier per K-step (16 MFMA/step at BM=128).
// A [M][K] f16, Bt [N][K] f16. 4 waves in 2x2.
// OUTMODE 0: write C as f16 + fused per-row min/max atomics (keys).
// OUTMODE 1: write C as f32 with bias+ReLU.
// ---------------------------------------------------------------------------
template<int BM, int BN, int MI, int NJ, int OUTMODE>
__global__ __launch_bounds__(256) void gemm_f16k64(
    const f16* __restrict__ A, const f16* __restrict__ Bt,
    const float* __restrict__ bias, void* __restrict__ Cout,
    unsigned* __restrict__ minkey, unsigned* __restrict__ maxkey,
    int M, int N, int K)
{
    constexpr int CA = BM / 32;      // A 1KB-chunks per wave per K-step
    constexpr int CB = BN / 32;
    __shared__ f16 lds[2][(BM + BN) * 64];

    const int t    = threadIdx.x;
    const int lane = t & 63;
    const int l15  = lane & 15;
    const int lhi  = lane >> 4;
    const int wid  = t >> 6;
    const int wm   = wid >> 1, wn = wid & 1;

    // chunked XCD swizzle: XCD k gets a contiguous tile range (nwg % 8 == 0)
    const int nwg  = gridDim.x * gridDim.y;
    const int flat = blockIdx.y * gridDim.x + blockIdx.x;
    const int swz  = (flat & 7) * (nwg >> 3) + (flat >> 3);
    const int m0   = (swz / gridDim.x) * BM;
    const int n0   = (swz % gridDim.x) * BN;

    auto stage = [&](int buf, int kt) {
        f16* base = &lds[buf][0];
#pragma unroll
        for (int j = 0; j < CA; ++j) {
            int c = wid * CA + j;    // chunk = 8 rows x 64 k
            const f16* g = A + (size_t)(m0 + c * 8 + (lane >> 3)) * K + kt + (lane & 7) * 8;
            __builtin_amdgcn_global_load_lds(
                (const __attribute__((address_space(1))) void*)g,
                (__attribute__((address_space(3))) void*)(base + c * 512),
                16, 0, 0);
        }
#pragma unroll
        for (int j = 0; j < CB; ++j) {
            int c = wid * CB + j;
            const f16* g = Bt + (size_t)(n0 + c * 8 + (lane >> 3)) * K + kt + (lane & 7) * 8;
            __builtin_amdgcn_global_load_lds(
                (const __attribute__((address_space(1))) void*)g,
                (__attribute__((address_space(3))) void*)(base + BM * 64 + c * 512),
                16, 0, 0);
        }
    };

    f32x4 acc[MI][NJ];
#pragma unroll
    for (int i = 0; i < MI; ++i)
#pragma unroll
        for (int j = 0; j < NJ; ++j) acc[i][j] = (f32x4)0.f;

    const int T = K / 64;
    stage(0, 0);
    __syncthreads();

    int cur = 0;
    for (int tt = 0; tt < T; ++tt) {
        if (tt + 1 < T) stage(cur ^ 1, (tt + 1) * 64);
        const f16* L = &lds[cur][0];
#pragma unroll
        for (int ks = 0; ks < 2; ++ks) {
            f16x8 bfr[NJ];
#pragma unroll
            for (int nj = 0; nj < NJ; ++nj)
                bfr[nj] = *(const f16x8*)
                    &L[BM * 64 + (wn * NJ * 16 + nj * 16 + l15) * 64 + ks * 32 + lhi * 8];
#pragma unroll
            for (int mi = 0; mi < MI; ++mi) {
                f16x8 afr = *(const f16x8*)
                    &L[(wm * MI * 16 + mi * 16 + l15) * 64 + ks * 32 + lhi * 8];
#pragma unroll
                for (int nj = 0; nj < NJ; ++nj)
                    acc[mi][nj] = __builtin_amdgcn_mfma_f32_16x16x32_f16(
                        afr, bfr[nj], acc[mi][nj], 0, 0, 0);
            }
        }
        __syncthreads();   // drains vmcnt(0): next tile fully staged
        cur ^= 1;
    }

    // epilogue: C/D map col = l15, row = lhi*4 + j
#pragma unroll
    for (int mi = 0; mi < MI; ++mi) {
        const int row0 = m0 + wm * MI * 16 + mi * 16 + lhi * 4;
        if (OUTMODE == 0) {
            f16* H = (f16*)Cout;
            float vmn[4], vmx[4];
#pragma unroll
            for (int nj = 0; nj < NJ; ++nj) {
                int col = n0 + wn * NJ * 16 + nj * 16 + l15;
                float bv = bias[col];
#pragma unroll
                for (int j = 0; j < 4; ++j) {
                    f16 hv = (f16)(acc[mi][nj][j] + bv);
                    H[(size_t)(row0 + j) * N + col] = hv;
                    float vr = (float)hv;      // min/max of the ROUNDED value
                    if (nj == 0) { vmn[j] = vr; vmx[j] = vr; }
                    else { vmn[j] = fminf(vmn[j], vr); vmx[j] = fmaxf(vmx[j], vr); }
                }
            }
#pragma unroll
            for (int j = 0; j < 4; ++j) {
#pragma unroll
                for (int d = 1; d < 16; d <<= 1) {
                    vmn[j] = fminf(vmn[j], __shfl_xor(vmn[j], d));
                    vmx[j] = fmaxf(vmx[j], __shfl_xor(vmx[j], d));
                }
            }
            if (l15 == 0) {
#pragma unroll
                for (int j = 0; j < 4; ++j) {
                    atomicMin(&minkey[row0 + j], fkey(vmn[j]));
                    atomicMax(&maxkey[row0 + j], fkey(vmx[j]));
                }
            }
        } else {
            float* O = (float*)Cout;
#pragma unroll
            for (int nj = 0; nj < NJ; ++nj) {
                int col = n0 + wn * NJ * 16 + nj * 16 + l15;
                float bv = bias[col];
#pragma unroll
                for (int j = 0; j < 4; ++j) {
                    float v = fmaxf(acc[mi][nj][j] + bv, 0.f);
                    O[(size_t)(row0 + j) * N + col] = v;
                }
            }
        }
    }
}

// ---------------------------------------------------------------------------
// Streaming norm+spline: u = (h-mn)/(mx-mn+1e-8), cubic B-spline de Boor,
// dot coeff window, +sp_bias -> f16. 2 rows per 256-thread block, 8 elem/thr.
// ---------------------------------------------------------------------------
__global__ __launch_bounds__(256) void norm_spline(
    const f16* __restrict__ H, const unsigned* __restrict__ minkey,
    const unsigned* __restrict__ maxkey, const float* __restrict__ coeff,
    const float* __restrict__ spb, f16* __restrict__ SPH)
{
    const int row = blockIdx.x * 2 + (threadIdx.x >> 7);
    const int t   = threadIdx.x & 127;
    const float mn = fdec(minkey[row]);
    const float mx = fdec(maxkey[row]);
    const float inv = 1.0f / (mx - mn + 1e-8f);

    f16x8 hv = *(const f16x8*)&H[(size_t)row * NEURONS + t * 8];
    const float hk = 1.0f / 15.0f;
    f16x8 o;

#pragma unroll
    for (int e = 0; e < 8; ++e) {
        const int n = t * 8 + e;
        const float u = ((float)hv[e] - mn) * inv;
        int ii = (int)floorf(u * 15.0f);
        ii = ii < 0 ? 0 : (ii > 14 ? 14 : ii);
        const int i = ii + 3;

        float Bv[4] = {1.f, 0.f, 0.f, 0.f};
#pragma unroll
        for (int p = 1; p <= 3; ++p) {
            const float dinv = 1.0f / ((float)p * hk);
            float nb[4];
#pragma unroll
            for (int j = 3; j >= 0; --j) {
                if (j > p) { nb[j] = 0.f; continue; }
                const int m = i - p + j;
                const float tm   = (float)(m - 3) * hk;
                const float tmp1 = (float)(m + p + 1 - 3) * hk;
                const float left  = (j > 0) ? (u - tm)   * Bv[j - 1] : 0.f;
                const float right = (j < p) ? (tmp1 - u) * Bv[j]     : 0.f;
                nb[j] = (left + right) * dinv;
            }
#pragma unroll
            for (int j = 0; j < 4; ++j) Bv[j] = nb[j];
        }

        const float* c = coeff + (size_t)n * 18 + ii;
        float sp = fmaf(Bv[0], c[0],
                   fmaf(Bv[1], c[1],
                   fmaf(Bv[2], c[2], Bv[3] * c[3]))) + spb[n];
        o[e] = (f16)sp;
    }
    *(f16x8*)&SPH[(size_t)row * NEURONS + t * 8] = o;
}

// ---------------------------------------------------------------------------
extern "C" void kernel_launch(void* const* d_in, const int* in_sizes, int n_in,
                              void* d_out, int out_size, void* d_ws, size_t ws_size,
                              hipStream_t stream)
{
    const float* x     = (const float*)d_in[0];
    const float* W1    = (const float*)d_in[1];
    const float* b1    = (const float*)d_in[2];
    const float* coeff = (const float*)d_in[3];
    const float* spb   = (const float*)d_in[4];
    const float* W2    = (const float*)d_in[5];
    const float* b2    = (const float*)d_in[6];
    float* out = (float*)d_out;

    char* ws = (char*)d_ws;
    f16*      h    = (f16*)ws;                       //  8 MB [4096][1024]
    f16*      sph  = (f16*)(ws + (8u  << 20));       //  8 MB [4096][1024]
    f16*      xh   = (f16*)(ws + (16u << 20));       //  4 MB [4096][512]
    f16*      W1t  = (f16*)(ws + (20u << 20));       //  1 MB [1024][512]
    f16*      W2t  = (f16*)(ws + (21u << 20));       //  1 MB [512][1024]
    unsigned* keys = (unsigned*)(ws + (22u << 20));  // 32 KB (min 4096 | max 4096)
    unsigned* minkey = keys;
    unsigned* maxkey = keys + 4096;

    prep<<<dim3(2080), 256, 0, stream>>>(x, xh, W1, W1t, W2, W2t, keys);

    // h(f16) = x @ W1 + b1, fused per-row min/max.  128x64 tiles -> 512 blocks
    gemm_f16k64<128, 64, 4, 2, 0><<<dim3(NEURONS / 64, M_ROWS / 128), 256, 0, stream>>>(
        xh, W1t, b1, h, minkey, maxkey, M_ROWS, NEURONS, IN_DIM);

    norm_spline<<<dim3(M_ROWS / 2), 256, 0, stream>>>(h, minkey, maxkey, coeff, spb, sph);

    // out = relu(sp @ W2 + b2).  64x64 tiles -> 512 blocks
    gemm_f16k64<64, 64, 2, 2, 1><<<dim3(OUT_DIM / 64, M_ROWS / 64), 256, 0, stream>>>(
        sph, W2t, b2, out, nullptr, nullptr, M_ROWS, OUT_DIM, NEURONS);
}